// Round 1
// baseline (3895.134 us; speedup 1.0000x reference)
//
#include <hip/hip_runtime.h>
#include <hip/hip_bf16.h>
#include <math.h>

#define T 1024
#define NLAYER 4
#define NHEAD 16
#define HEAD 64
#define DIN 2048
#define MHEAD 32
#define DSTATE 64
#define FFH 4096
#define NWIN 4256
#define CCONV 2176
#define VOCABSZ 32000
#define CHUNK 64
#define NCHUNK 16

typedef unsigned short u16;
typedef __attribute__((ext_vector_type(8))) short s16x8;
typedef __attribute__((ext_vector_type(4))) float f32x4;

__device__ inline u16 f2bf(float f) {
  union { float f; unsigned u; } v; v.f = f;
  return (u16)((v.u + 0x7FFF + ((v.u >> 16) & 1)) >> 16);
}
__device__ inline float bf2f(u16 s) {
  union { unsigned u; float f; } v; v.u = ((unsigned)s) << 16;
  return v.f;
}
__device__ inline float sigf(float x) { return 1.f / (1.f + expf(-x)); }

__device__ inline float block_sum(float v, float* sb) {
  #pragma unroll
  for (int o = 32; o; o >>= 1) v += __shfl_down(v, o);
  int w = threadIdx.x >> 6;
  if ((threadIdx.x & 63) == 0) sb[w] = v;
  __syncthreads();
  float s = sb[0] + sb[1] + sb[2] + sb[3];
  __syncthreads();
  return s;
}

// ---------------- embedding gather ----------------
__global__ __launch_bounds__(256) void k_embed(const int* x, const float* embed, float* h) {
  int t = blockIdx.x, d = threadIdx.x;
  int row = x[t];
  const float4* src = (const float4*)(embed + (size_t)row * 1024);
  float4* dst = (float4*)(h + (size_t)t * 1024);
  dst[d] = src[d];
}

// ---------------- rmsnorm (width 1024) -> bf16 ----------------
__global__ __launch_bounds__(256) void k_rmsnorm(const float* in, const float* w, u16* out) {
  __shared__ float sb[8];
  int t = blockIdx.x, tid = threadIdx.x;
  float4 v = *(const float4*)&in[(size_t)t * 1024 + tid * 4];
  float ss = v.x * v.x + v.y * v.y + v.z * v.z + v.w * v.w;
  float tot = block_sum(ss, sb);
  float rn = rsqrtf(tot / 1024.f + 1e-6f);
  int c = tid * 4;
  size_t b = (size_t)t * 1024 + c;
  out[b + 0] = f2bf(v.x * rn * w[c + 0]);
  out[b + 1] = f2bf(v.y * rn * w[c + 1]);
  out[b + 2] = f2bf(v.z * rn * w[c + 2]);
  out[b + 3] = f2bf(v.w * rn * w[c + 3]);
}

// ---------------- GEMM: C(MxN) = A(bf16, MxK) @ B(f32) ----------------
enum { EPI_F32 = 0, EPI_LDECAY = 1, EPI_SILU = 2, EPI_GELU_BF16 = 3, EPI_ADD = 4 };

template <int EPI, bool BT>
__global__ __launch_bounds__(256) void k_gemm(const u16* __restrict__ A,
                                              const float* __restrict__ B,
                                              void* __restrict__ Cout, int N, int K,
                                              int ldb, const float* __restrict__ aux) {
  __shared__ u16 As[64][72];
  __shared__ u16 Bs[64][72];
  int tid = threadIdx.x;
  int m0 = blockIdx.x * 64, n0 = blockIdx.y * 64;
  int lane = tid & 63, wid = tid >> 6;
  int wr = (wid >> 1) * 32, wc = (wid & 1) * 32;
  int lr = lane & 15, lk8 = (lane >> 4) * 8;
  f32x4 acc00 = {}, acc01 = {}, acc10 = {}, acc11 = {};
  for (int k0 = 0; k0 < K; k0 += 64) {
    __syncthreads();
    #pragma unroll
    for (int it = 0; it < 2; ++it) {
      int idx = it * 256 + tid;
      int r = idx >> 3, c8 = (idx & 7) * 8;
      *(uint4*)&As[r][c8] = *(const uint4*)&A[(size_t)(m0 + r) * K + k0 + c8];
    }
    if (!BT) {
      #pragma unroll
      for (int it = 0; it < 4; ++it) {
        int idx = it * 256 + tid;
        int kk = idx >> 4, nc = (idx & 15) * 4;
        int col = n0 + nc;
        float4 v;
        if (col + 3 < N) v = *(const float4*)&B[(size_t)(k0 + kk) * ldb + col];
        else {
          v.x = (col < N) ? B[(size_t)(k0 + kk) * ldb + col] : 0.f;
          v.y = (col + 1 < N) ? B[(size_t)(k0 + kk) * ldb + col + 1] : 0.f;
          v.z = (col + 2 < N) ? B[(size_t)(k0 + kk) * ldb + col + 2] : 0.f;
          v.w = 0.f;
        }
        Bs[nc + 0][kk] = f2bf(v.x); Bs[nc + 1][kk] = f2bf(v.y);
        Bs[nc + 2][kk] = f2bf(v.z); Bs[nc + 3][kk] = f2bf(v.w);
      }
    } else {
      #pragma unroll
      for (int it = 0; it < 4; ++it) {
        int idx = it * 256 + tid;
        int nr = idx >> 4, kc = (idx & 15) * 4;
        float4 v = {0.f, 0.f, 0.f, 0.f};
        if (n0 + nr < N) v = *(const float4*)&B[(size_t)(n0 + nr) * ldb + k0 + kc];
        Bs[nr][kc + 0] = f2bf(v.x); Bs[nr][kc + 1] = f2bf(v.y);
        Bs[nr][kc + 2] = f2bf(v.z); Bs[nr][kc + 3] = f2bf(v.w);
      }
    }
    __syncthreads();
    #pragma unroll
    for (int kb = 0; kb < 64; kb += 32) {
      s16x8 a0 = *(const s16x8*)&As[wr + lr][kb + lk8];
      s16x8 a1 = *(const s16x8*)&As[wr + 16 + lr][kb + lk8];
      s16x8 b0 = *(const s16x8*)&Bs[wc + lr][kb + lk8];
      s16x8 b1 = *(const s16x8*)&Bs[wc + 16 + lr][kb + lk8];
      acc00 = __builtin_amdgcn_mfma_f32_16x16x32_bf16(a0, b0, acc00, 0, 0, 0);
      acc01 = __builtin_amdgcn_mfma_f32_16x16x32_bf16(a0, b1, acc01, 0, 0, 0);
      acc10 = __builtin_amdgcn_mfma_f32_16x16x32_bf16(a1, b0, acc10, 0, 0, 0);
      acc11 = __builtin_amdgcn_mfma_f32_16x16x32_bf16(a1, b1, acc11, 0, 0, 0);
    }
  }
  auto emit = [&](f32x4 a, int row, int col) {
    if (col >= N) return;
    #pragma unroll
    for (int r_ = 0; r_ < 4; ++r_) {
      float v = a[r_];
      size_t idx = (size_t)(row + r_) * N + col;
      if constexpr (EPI == EPI_F32) ((float*)Cout)[idx] = v;
      else if constexpr (EPI == EPI_LDECAY) ((float*)Cout)[idx] = -expf(v + aux[col]);
      else if constexpr (EPI == EPI_SILU) ((float*)Cout)[idx] = v * sigf(v);
      else if constexpr (EPI == EPI_GELU_BF16)
        ((u16*)Cout)[idx] = f2bf(0.5f * v * (1.f + erff(v * 0.70710678118654752f)));
      else if constexpr (EPI == EPI_ADD) ((float*)Cout)[idx] += v;
    }
  };
  int rb = m0 + wr + (lane >> 4) * 4;
  int cb = n0 + wc + lr;
  emit(acc00, rb, cb);       emit(acc01, rb, cb + 16);
  emit(acc10, rb + 16, cb);  emit(acc11, rb + 16, cb + 16);
}

// ---------------- rwkv: per-chunk cumulative decays ----------------
// g_ex[i] = sum_{m<i} ld[m]  (per k).  rt = r*exp(g_ex).  khT[k][i] = k_i*exp(gL-g[i+1]).
__global__ void k_rwkv_pre(const float* rbuf, const float* kbuf, const float* ldbuf,
                           float* gex, u16* rt, u16* khT, float* eL) {
  int c = blockIdx.x, h = blockIdx.y, k = threadIdx.x;
  size_t col = (size_t)h * 64 + k;
  float g = 0.f;
  for (int i = 0; i < 64; ++i) {
    size_t idx = (size_t)(c * 64 + i) * 1024 + col;
    gex[idx] = g;
    rt[idx] = f2bf(rbuf[idx] * expf(g));
    g += ldbuf[idx];
  }
  float gL = g;
  eL[((size_t)c * 16 + h) * 64 + k] = expf(gL);
  g = 0.f;
  for (int i = 0; i < 64; ++i) {
    size_t idx = (size_t)(c * 64 + i) * 1024 + col;
    g += ldbuf[idx];
    khT[(((size_t)c * 16 + h) * 64 + k) * 64 + i] = f2bf(kbuf[idx] * expf(fminf(gL - g, 0.f)));
  }
}

// intra-chunk scores: G[i][s] = sum_k r_i k_s exp(g_i - g_{s+1}) (s<i); diag: sum_k r_i u_k k_i
__global__ __launch_bounds__(256) void k_rwkvG(const float* rbuf, const float* kbuf,
                                               const float* gex, const float* u, u16* G) {
  __shared__ float rS[64][65], kS[64][65], gS[64][65];
  __shared__ float uS[64];
  int c = blockIdx.x, h = blockIdx.y, tid = threadIdx.x;
  #pragma unroll
  for (int it = 0; it < 4; ++it) {
    int idx = it * 256 + tid;
    int r = idx >> 4, c4 = (idx & 15) * 4;
    size_t base = (size_t)(c * 64 + r) * 1024 + h * 64 + c4;
    float4 rv = *(const float4*)&rbuf[base];
    float4 kv = *(const float4*)&kbuf[base];
    float4 gv = *(const float4*)&gex[base];
    rS[r][c4] = rv.x; rS[r][c4+1] = rv.y; rS[r][c4+2] = rv.z; rS[r][c4+3] = rv.w;
    kS[r][c4] = kv.x; kS[r][c4+1] = kv.y; kS[r][c4+2] = kv.z; kS[r][c4+3] = kv.w;
    gS[r][c4] = gv.x; gS[r][c4+1] = gv.y; gS[r][c4+2] = gv.z; gS[r][c4+3] = gv.w;
  }
  if (tid < 64) uS[tid] = u[h * 64 + tid];
  __syncthreads();
  int i = tid & 63, sg = tid >> 6;
  float acc[16] = {};
  float accd = 0.f;
  for (int k = 0; k < 64; ++k) {
    float rv = rS[i][k], gi = gS[i][k];
    accd += rv * uS[k] * kS[i][k];
    #pragma unroll
    for (int j = 0; j < 16; ++j) {
      int s = sg * 16 + j;
      int sp1 = (s < 63) ? s + 1 : 63;
      acc[j] += rv * kS[s][k] * expf(fminf(gi - gS[sp1][k], 0.f));
    }
  }
  #pragma unroll
  for (int j = 0; j < 16; ++j) {
    int s = sg * 16 + j;
    float v = (s < i) ? acc[j] : ((s == i) ? accd : 0.f);
    G[(((size_t)c * 16 + h) * 64 + i) * 64 + s] = f2bf(v);
  }
}

// sequential over chunks; per-head block carries S (f32 in LDS).
// O = rt@S_in + G@V ;  S = diag(eL)*S_in + khT@V
__global__ __launch_bounds__(256) void k_rwkv_phaseB(const u16* rt, const u16* G,
                                                     const u16* khT, const float* vbuf,
                                                     const float* eL, float* obuf) {
  __shared__ u16 rtS[64][72];
  __shared__ u16 GS[64][72];
  __shared__ u16 khS[64][72];
  __shared__ u16 vtS[64][72];
  __shared__ float ST[64][68];
  __shared__ float eLs[64];
  int h = blockIdx.x, tid = threadIdx.x;
  int lane = tid & 63, wid = tid >> 6;
  int lr = lane & 15, lk8 = (lane >> 4) * 8;
  for (int i = tid; i < 64 * 68; i += 256) ((float*)ST)[i] = 0.f;
  for (int c = 0; c < 16; ++c) {
    __syncthreads();
    #pragma unroll
    for (int it = 0; it < 2; ++it) {
      int idx = it * 256 + tid;
      int i = idx >> 3, c8 = (idx & 7) * 8;
      *(uint4*)&rtS[i][c8] = *(const uint4*)&rt[(size_t)(c * 64 + i) * 1024 + h * 64 + c8];
      *(uint4*)&GS[i][c8]  = *(const uint4*)&G[(((size_t)c * 16 + h) * 64 + i) * 64 + c8];
      *(uint4*)&khS[i][c8] = *(const uint4*)&khT[(((size_t)c * 16 + h) * 64 + i) * 64 + c8];
    }
    #pragma unroll
    for (int it = 0; it < 4; ++it) {
      int idx = it * 256 + tid;
      int s = idx >> 4, v4 = (idx & 15) * 4;
      float4 vv = *(const float4*)&vbuf[(size_t)(c * 64 + s) * 1024 + h * 64 + v4];
      vtS[v4 + 0][s] = f2bf(vv.x); vtS[v4 + 1][s] = f2bf(vv.y);
      vtS[v4 + 2][s] = f2bf(vv.z); vtS[v4 + 3][s] = f2bf(vv.w);
    }
    if (tid < 64) eLs[tid] = eL[((size_t)c * 16 + h) * 64 + tid];
    __syncthreads();
    f32x4 accO[4] = {}; f32x4 accS[4] = {};
    #pragma unroll
    for (int kb = 0; kb < 64; kb += 32) {
      s16x8 aR = *(const s16x8*)&rtS[wid * 16 + lr][kb + lk8];
      s16x8 aG = *(const s16x8*)&GS[wid * 16 + lr][kb + lk8];
      s16x8 aK = *(const s16x8*)&khS[wid * 16 + lr][kb + lk8];
      #pragma unroll
      for (int nt = 0; nt < 4; ++nt) {
        s16x8 bS;
        const float* sp = &ST[nt * 16 + lr][kb + lk8];
        #pragma unroll
        for (int j = 0; j < 8; ++j) bS[j] = (short)f2bf(sp[j]);
        s16x8 bV = *(const s16x8*)&vtS[nt * 16 + lr][kb + lk8];
        accO[nt] = __builtin_amdgcn_mfma_f32_16x16x32_bf16(aR, bS, accO[nt], 0, 0, 0);
        accO[nt] = __builtin_amdgcn_mfma_f32_16x16x32_bf16(aG, bV, accO[nt], 0, 0, 0);
        accS[nt] = __builtin_amdgcn_mfma_f32_16x16x32_bf16(aK, bV, accS[nt], 0, 0, 0);
      }
    }
    __syncthreads();
    #pragma unroll
    for (int nt = 0; nt < 4; ++nt) {
      #pragma unroll
      for (int r_ = 0; r_ < 4; ++r_) {
        int i = wid * 16 + (lane >> 4) * 4 + r_;
        int v = nt * 16 + lr;
        obuf[(size_t)(c * 64 + i) * 1024 + h * 64 + v] = accO[nt][r_];
      }
    }
    #pragma unroll
    for (int nt = 0; nt < 4; ++nt) {
      #pragma unroll
      for (int r_ = 0; r_ < 4; ++r_) {
        int kd = wid * 16 + (lane >> 4) * 4 + r_;
        int v = nt * 16 + lr;
        ST[v][kd] = eLs[kd] * ST[v][kd] + accS[nt][r_];
      }
    }
  }
}

// ---------------- o*g -> bf16 ----------------
__global__ __launch_bounds__(256) void k_og(const float* o, const float* g, u16* og) {
  size_t idx = (size_t)blockIdx.x * 256 + threadIdx.x;
  float4 ov = *(const float4*)&o[idx * 4];
  float4 gv = *(const float4*)&g[idx * 4];
  og[idx * 4 + 0] = f2bf(ov.x * gv.x);
  og[idx * 4 + 1] = f2bf(ov.y * gv.y);
  og[idx * 4 + 2] = f2bf(ov.z * gv.z);
  og[idx * 4 + 3] = f2bf(ov.w * gv.w);
}

// ---------------- causal depthwise conv (K=4) + silu ----------------
__global__ void k_conv(const float* zx, const float* cw, float* xc) {
  int c = blockIdx.x * 256 + threadIdx.x;
  int t = blockIdx.y;
  if (c >= CCONV) return;
  float4 w = *(const float4*)&cw[c * 4];
  float acc = 0.f;
  if (t - 3 >= 0) acc += zx[(size_t)(t - 3) * NWIN + 2048 + c] * w.x;
  if (t - 2 >= 0) acc += zx[(size_t)(t - 2) * NWIN + 2048 + c] * w.y;
  if (t - 1 >= 0) acc += zx[(size_t)(t - 1) * NWIN + 2048 + c] * w.z;
  acc += zx[(size_t)t * NWIN + 2048 + c] * w.w;
  xc[(size_t)t * CCONV + c] = acc * sigf(acc);
}

// ---------------- dt softplus + log dA ----------------
__global__ void k_dt(const float* zx, const float* dt_bias, const float* A_log,
                     float* dtb, float* ldA) {
  int idx = blockIdx.x * 256 + threadIdx.x;
  int t = idx >> 5, j = idx & 31;
  float x = zx[(size_t)t * NWIN + 4224 + j] + dt_bias[j];
  float sp = (x > 20.f) ? x : log1pf(expf(x));
  dtb[idx] = sp;
  ldA[idx] = -sp * expf(A_log[j]);
}

// ---------------- per-chunk inclusive prefix of ldA ----------------
__global__ void k_la(const float* ldA, float* la) {
  int c = blockIdx.x, h = threadIdx.x;
  if (h >= 32) return;
  float g = 0.f;
  for (int i = 0; i < 64; ++i) {
    g += ldA[(size_t)(c * 64 + i) * 32 + h];
    la[((size_t)c * 32 + h) * 64 + i] = g;
  }
}

// ---------------- BC[i][s] = B_s . C_i (shared across heads) ----------------
__global__ __launch_bounds__(256) void k_bc(const float* xc, float* BC) {
  __shared__ float Bc[64][65], Cc[64][65];
  int c = blockIdx.x, tid = threadIdx.x;
  #pragma unroll
  for (int it = 0; it < 4; ++it) {
    int idx = it * 256 + tid;
    int r = idx >> 4, c4 = (idx & 15) * 4;
    float4 b4 = *(const float4*)&xc[(size_t)(c * 64 + r) * CCONV + 2048 + c4];
    float4 cv = *(const float4*)&xc[(size_t)(c * 64 + r) * CCONV + 2112 + c4];
    Bc[r][c4] = b4.x; Bc[r][c4+1] = b4.y; Bc[r][c4+2] = b4.z; Bc[r][c4+3] = b4.w;
    Cc[r][c4] = cv.x; Cc[r][c4+1] = cv.y; Cc[r][c4+2] = cv.z; Cc[r][c4+3] = cv.w;
  }
  __syncthreads();
  int i = tid & 63, sg = tid >> 6;
  float acc[16] = {};
  for (int d = 0; d < 64; ++d) {
    float cv = Cc[i][d];
    #pragma unroll
    for (int j = 0; j < 16; ++j) acc[j] += Bc[sg * 16 + j][d] * cv;
  }
  #pragma unroll
  for (int j = 0; j < 16; ++j)
    BC[((size_t)c * 64 + i) * 64 + sg * 16 + j] = acc[j];
}

// ---------------- M[i][s] = exp(la_i - la_s)*dt_s*BC[i][s], s<=i ----------------
__global__ __launch_bounds__(256) void k_m(const float* la, const float* dtb,
                                           const float* BC, u16* Mb) {
  int c = blockIdx.x, h = blockIdx.y, tid = threadIdx.x;
  int i = tid & 63, sg = tid >> 6;
  float lai = la[((size_t)c * 32 + h) * 64 + i];
  #pragma unroll
  for (int j = 0; j < 16; ++j) {
    int s = sg * 16 + j;
    float v = 0.f;
    if (s <= i) {
      float las = la[((size_t)c * 32 + h) * 64 + s];
      v = expf(fminf(lai - las, 0.f)) * dtb[(size_t)(c * 64 + s) * 32 + h] *
          BC[((size_t)c * 64 + i) * 64 + s];
    }
    Mb[(((size_t)c * 32 + h) * 64 + i) * 64 + s] = f2bf(v);
  }
}

// ---------------- mamba sequential chunk loop per head ----------------
// Y = M@X + (e^{la_i} C)@h_in^T ;  h = e^{la_63} h_in + Xhat^T @ B
__global__ __launch_bounds__(256) void k_mamba_phaseB(const u16* Mb, const float* la,
                                                      const float* dtb, const float* xc,
                                                      float* ymb) {
  __shared__ u16 MS[64][72];
  __shared__ u16 CtS[64][72];
  __shared__ u16 XT[64][72];
  __shared__ u16 BTs[64][72];
  __shared__ float hS[64][68];
  __shared__ float fS[64];
  __shared__ float eLastS;
  int h = blockIdx.x, tid = threadIdx.x;
  int lane = tid & 63, wid = tid >> 6;
  int lr = lane & 15, lk8 = (lane >> 4) * 8;
  for (int i = tid; i < 64 * 68; i += 256) ((float*)hS)[i] = 0.f;
  for (int c = 0; c < 16; ++c) {
    __syncthreads();
    #pragma unroll
    for (int it = 0; it < 2; ++it) {
      int idx = it * 256 + tid;
      int i = idx >> 3, c8 = (idx & 7) * 8;
      *(uint4*)&MS[i][c8] = *(const uint4*)&Mb[(((size_t)c * 32 + h) * 64 + i) * 64 + c8];
    }
    #pragma unroll
    for (int it = 0; it < 4; ++it) {
      int idx = it * 256 + tid;
      int i = idx >> 4, s4 = (idx & 15) * 4;
      float e = expf(la[((size_t)c * 32 + h) * 64 + i]);
      float4 cv = *(const float4*)&xc[(size_t)(c * 64 + i) * CCONV + 2112 + s4];
      CtS[i][s4] = f2bf(e * cv.x); CtS[i][s4+1] = f2bf(e * cv.y);
      CtS[i][s4+2] = f2bf(e * cv.z); CtS[i][s4+3] = f2bf(e * cv.w);
      float4 xv = *(const float4*)&xc[(size_t)(c * 64 + i) * CCONV + h * 64 + s4];
      XT[s4][i] = f2bf(xv.x); XT[s4+1][i] = f2bf(xv.y);
      XT[s4+2][i] = f2bf(xv.z); XT[s4+3][i] = f2bf(xv.w);
      float4 bv = *(const float4*)&xc[(size_t)(c * 64 + i) * CCONV + 2048 + s4];
      BTs[s4][i] = f2bf(bv.x); BTs[s4+1][i] = f2bf(bv.y);
      BTs[s4+2][i] = f2bf(bv.z); BTs[s4+3][i] = f2bf(bv.w);
    }
    if (tid < 64) {
      float la63 = la[((size_t)c * 32 + h) * 64 + 63];
      float las = la[((size_t)c * 32 + h) * 64 + tid];
      fS[tid] = dtb[(size_t)(c * 64 + tid) * 32 + h] * expf(fminf(la63 - las, 0.f));
      if (tid == 0) eLastS = expf(la63);
    }
    __syncthreads();
    f32x4 accY[4] = {}; f32x4 accU[4] = {};
    #pragma unroll
    for (int kb = 0; kb < 64; kb += 32) {
      s16x8 aM = *(const s16x8*)&MS[wid * 16 + lr][kb + lk8];
      s16x8 aC = *(const s16x8*)&CtS[wid * 16 + lr][kb + lk8];
      s16x8 aX;
      {
        const u16* xp = &XT[wid * 16 + lr][kb + lk8];
        #pragma unroll
        for (int j = 0; j < 8; ++j) aX[j] = (short)f2bf(fS[kb + lk8 + j] * bf2f(xp[j]));
      }
      #pragma unroll
      for (int nt = 0; nt < 4; ++nt) {
        s16x8 bX = *(const s16x8*)&XT[nt * 16 + lr][kb + lk8];
        s16x8 bH;
        const float* hp = &hS[nt * 16 + lr][kb + lk8];
        #pragma unroll
        for (int j = 0; j < 8; ++j) bH[j] = (short)f2bf(hp[j]);
        s16x8 bB = *(const s16x8*)&BTs[nt * 16 + lr][kb + lk8];
        accY[nt] = __builtin_amdgcn_mfma_f32_16x16x32_bf16(aM, bX, accY[nt], 0, 0, 0);
        accY[nt] = __builtin_amdgcn_mfma_f32_16x16x32_bf16(aC, bH, accY[nt], 0, 0, 0);
        accU[nt] = __builtin_amdgcn_mfma_f32_16x16x32_bf16(aX, bB, accU[nt], 0, 0, 0);
      }
    }
    __syncthreads();
    #pragma unroll
    for (int nt = 0; nt < 4; ++nt) {
      #pragma unroll
      for (int r_ = 0; r_ < 4; ++r_) {
        int i = wid * 16 + (lane >> 4) * 4 + r_;
        int p = nt * 16 + lr;
        ymb[(size_t)(c * 64 + i) * 2048 + h * 64 + p] = accY[nt][r_];
      }
    }
    #pragma unroll
    for (int nt = 0; nt < 4; ++nt) {
      #pragma unroll
      for (int r_ = 0; r_ < 4; ++r_) {
        int p = wid * 16 + (lane >> 4) * 4 + r_;
        int s = nt * 16 + lr;
        hS[p][s] = eLastS * hS[p][s] + accU[nt][r_];
      }
    }
  }
}

// ---------------- ym: +Dskip*x, *silu(z), rmsnorm(2048) -> bf16 ----------------
__global__ __launch_bounds__(256) void k_ymn(const float* ymb, const float* xc,
                                             const float* zx, const float* Dsk,
                                             const float* mnw, u16* out) {
  __shared__ float sb[8];
  int t = blockIdx.x, tid = threadIdx.x;
  float vals[8];
  float ss = 0.f;
  #pragma unroll
  for (int j = 0; j < 8; ++j) {
    int cidx = j * 256 + tid;
    float yv = ymb[(size_t)t * 2048 + cidx] + Dsk[cidx >> 6] * xc[(size_t)t * CCONV + cidx];
    float zv = zx[(size_t)t * NWIN + cidx];
    float val = yv * zv * sigf(zv);
    vals[j] = val;
    ss += val * val;
  }
  float tot = block_sum(ss, sb);
  float rn = rsqrtf(tot / 2048.f + 1e-6f);
  #pragma unroll
  for (int j = 0; j < 8; ++j) {
    int cidx = j * 256 + tid;
    out[(size_t)t * 2048 + cidx] = f2bf(vals[j] * rn * mnw[cidx]);
  }
}

// ---------------- gate + residual ----------------
__global__ __launch_bounds__(256) void k_gate(const float* rw, const float* mb,
                                              const float* gw, const float* gb, float* h) {
  __shared__ float sb[8];
  int t = blockIdx.x, tid = threadIdx.x;
  float s = 0.f;
  #pragma unroll
  for (int j = 0; j < 4; ++j) {
    int d = j * 256 + tid;
    s += rw[(size_t)t * 1024 + d] * gw[d] + mb[(size_t)t * 1024 + d] * gw[1024 + d];
  }
  float tot = block_sum(s, sb);
  float gate = sigf(tot + gb[0]);
  #pragma unroll
  for (int j = 0; j < 4; ++j) {
    int d = j * 256 + tid;
    h[(size_t)t * 1024 + d] += gate * rw[(size_t)t * 1024 + d] +
                               (1.f - gate) * mb[(size_t)t * 1024 + d];
  }
}

// =======================================================================
extern "C" void kernel_launch(void* const* d_in, const int* in_sizes, int n_in,
                              void* d_out, int out_size, void* d_ws, size_t ws_size,
                              hipStream_t stream) {
  const int*   x       = (const int*)d_in[0];
  const float* embed   = (const float*)d_in[1];
  const float* ln_w    = (const float*)d_in[2];
  const float* Wr      = (const float*)d_in[3];
  const float* Wk      = (const float*)d_in[4];
  const float* Wv      = (const float*)d_in[5];
  const float* Ww      = (const float*)d_in[6];
  const float* w_bias  = (const float*)d_in[7];
  const float* u       = (const float*)d_in[8];
  const float* Wg      = (const float*)d_in[9];
  const float* Wo      = (const float*)d_in[10];
  const float* Win     = (const float*)d_in[11];
  const float* conv_w  = (const float*)d_in[12];
  const float* dt_bias = (const float*)d_in[13];
  const float* A_log   = (const float*)d_in[14];
  const float* Dskip   = (const float*)d_in[15];
  const float* mnorm_w = (const float*)d_in[16];
  const float* Wout_m  = (const float*)d_in[17];
  const float* gate_w  = (const float*)d_in[18];
  const float* gate_b  = (const float*)d_in[19];
  const float* ffn_ln  = (const float*)d_in[20];
  const float* W1      = (const float*)d_in[21];
  const float* W2      = (const float*)d_in[22];
  const float* ln_out  = (const float*)d_in[23];

  char* p = (char*)d_ws;
  auto alloc = [&](size_t bytes) {
    char* r = p;
    p += (bytes + 255) & ~(size_t)255;
    return r;
  };
  float* h        = (float*)alloc((size_t)T * 1024 * 4);
  u16*   nx       = (u16*)alloc((size_t)T * 1024 * 2);
  float* rbuf     = (float*)alloc((size_t)T * 1024 * 4);
  float* kbuf     = (float*)alloc((size_t)T * 1024 * 4);
  float* vbuf     = (float*)alloc((size_t)T * 1024 * 4);
  float* ldbuf    = (float*)alloc((size_t)T * 1024 * 4);
  float* gbuf     = (float*)alloc((size_t)T * 1024 * 4);
  float* zx       = (float*)alloc((size_t)T * NWIN * 4);
  float* gex      = (float*)alloc((size_t)T * 1024 * 4);
  u16*   rt       = (u16*)alloc((size_t)T * 1024 * 2);
  u16*   khT      = (u16*)alloc((size_t)T * 1024 * 2);
  float* eL       = (float*)alloc((size_t)NCHUNK * 16 * 64 * 4);
  u16*   Gb       = (u16*)alloc((size_t)NCHUNK * 16 * 64 * 64 * 2);
  float* obuf     = (float*)alloc((size_t)T * 1024 * 4);
  u16*   og       = (u16*)alloc((size_t)T * 1024 * 2);
  float* out_rwkv = (float*)alloc((size_t)T * 1024 * 4);
  float* xc       = (float*)alloc((size_t)T * CCONV * 4);
  float* dtb      = (float*)alloc((size_t)T * 32 * 4);
  float* ldA      = (float*)alloc((size_t)T * 32 * 4);
  float* la       = (float*)alloc((size_t)NCHUNK * 32 * 64 * 4);
  float* BC       = (float*)alloc((size_t)NCHUNK * 64 * 64 * 4);
  u16*   Mb       = (u16*)alloc((size_t)NCHUNK * 32 * 64 * 64 * 2);
  float* ymb      = (float*)alloc((size_t)T * 2048 * 4);
  u16*   ymn      = (u16*)alloc((size_t)T * 2048 * 2);
  float* out_mam  = (float*)alloc((size_t)T * 1024 * 4);
  u16*   ffa      = (u16*)alloc((size_t)T * FFH * 2);

  k_embed<<<1024, 256, 0, stream>>>(x, embed, h);

  for (int l = 0; l < NLAYER; ++l) {
    size_t oW = (size_t)l * 1024 * 1024;
    k_rmsnorm<<<1024, 256, 0, stream>>>(h, ln_w + l * 1024, nx);
    k_gemm<EPI_F32, false><<<dim3(16, 16), 256, 0, stream>>>(nx, Wr + oW, rbuf, 1024, 1024, 1024, nullptr);
    k_gemm<EPI_F32, false><<<dim3(16, 16), 256, 0, stream>>>(nx, Wk + oW, kbuf, 1024, 1024, 1024, nullptr);
    k_gemm<EPI_F32, false><<<dim3(16, 16), 256, 0, stream>>>(nx, Wv + oW, vbuf, 1024, 1024, 1024, nullptr);
    k_gemm<EPI_LDECAY, false><<<dim3(16, 16), 256, 0, stream>>>(nx, Ww + oW, ldbuf, 1024, 1024, 1024, w_bias + l * 1024);
    k_gemm<EPI_SILU, false><<<dim3(16, 16), 256, 0, stream>>>(nx, Wg + oW, gbuf, 1024, 1024, 1024, nullptr);
    k_gemm<EPI_F32, false><<<dim3(16, 67), 256, 0, stream>>>(nx, Win + (size_t)l * 1024 * NWIN, zx, NWIN, 1024, NWIN, nullptr);

    // rwkv branch
    k_rwkv_pre<<<dim3(16, 16), 64, 0, stream>>>(rbuf, kbuf, ldbuf, gex, rt, khT, eL);
    k_rwkvG<<<dim3(16, 16), 256, 0, stream>>>(rbuf, kbuf, gex, u + (size_t)l * 1024, Gb);
    k_rwkv_phaseB<<<16, 256, 0, stream>>>(rt, Gb, khT, vbuf, eL, obuf);
    k_og<<<1024, 256, 0, stream>>>(obuf, gbuf, og);
    k_gemm<EPI_F32, false><<<dim3(16, 16), 256, 0, stream>>>(og, Wo + oW, out_rwkv, 1024, 1024, 1024, nullptr);

    // mamba branch
    k_conv<<<dim3(9, 1024), 256, 0, stream>>>(zx, conv_w + (size_t)l * CCONV * 4, xc);
    k_dt<<<128, 256, 0, stream>>>(zx, dt_bias + l * 32, A_log + l * 32, dtb, ldA);
    k_la<<<16, 64, 0, stream>>>(ldA, la);
    k_bc<<<16, 256, 0, stream>>>(xc, BC);
    k_m<<<dim3(16, 32), 256, 0, stream>>>(la, dtb, BC, Mb);
    k_mamba_phaseB<<<32, 256, 0, stream>>>(Mb, la, dtb, xc, ymb);
    k_ymn<<<1024, 256, 0, stream>>>(ymb, xc, zx, Dskip + l * 32, mnorm_w + (size_t)l * 2048, ymn);
    k_gemm<EPI_F32, false><<<dim3(16, 16), 256, 0, stream>>>(ymn, Wout_m + (size_t)l * 2048 * 1024, out_mam, 1024, 2048, 1024, nullptr);

    // gate + residual
    k_gate<<<1024, 256, 0, stream>>>(out_rwkv, out_mam, gate_w + (size_t)l * 2048, gate_b + l, h);

    // FFN
    k_rmsnorm<<<1024, 256, 0, stream>>>(h, ffn_ln + l * 1024, nx);
    k_gemm<EPI_GELU_BF16, false><<<dim3(16, 64), 256, 0, stream>>>(nx, W1 + (size_t)l * 1024 * FFH, ffa, FFH, 1024, FFH, nullptr);
    k_gemm<EPI_ADD, false><<<dim3(16, 16), 256, 0, stream>>>(ffa, W2 + (size_t)l * FFH * 1024, h, 1024, FFH, 1024, nullptr);
  }

  k_rmsnorm<<<1024, 256, 0, stream>>>(h, ln_out, nx);
  k_gemm<EPI_F32, true><<<dim3(16, 500), 256, 0, stream>>>(nx, embed, d_out, VOCABSZ, 1024, 1024, nullptr);
}

// Round 2
// 1829.100 us; speedup vs baseline: 2.1295x; 2.1295x over previous
//
#include <hip/hip_runtime.h>
#include <hip/hip_bf16.h>
#include <math.h>

#define T 1024
#define NLAYER 4
#define NHEAD 16
#define HEAD 64
#define DIN 2048
#define MHEAD 32
#define DSTATE 64
#define FFH 4096
#define NWIN 4256
#define CCONV 2176
#define VOCABSZ 32000
#define NCHUNK 16
#define PKROWS 9472   /* 5*1024 + 4256 padded to mult of 128 */
#define PKN 9376

typedef unsigned short u16;
typedef __attribute__((ext_vector_type(8))) short s16x8;
typedef __attribute__((ext_vector_type(4))) float f32x4;

__device__ inline u16 f2bf(float f) {
  union { float f; unsigned u; } v; v.f = f;
  return (u16)((v.u + 0x7FFF + ((v.u >> 16) & 1)) >> 16);
}
__device__ inline float bf2f(u16 s) {
  union { unsigned u; float f; } v; v.u = ((unsigned)s) << 16;
  return v.f;
}
__device__ inline float sigf(float x) { return 1.f / (1.f + expf(-x)); }

// global -> LDS direct (16B per lane). dest = uniform base + lane*16.
__device__ inline void gload16(const void* g, void* l) {
  __builtin_amdgcn_global_load_lds(
      (__attribute__((address_space(1))) void*)(size_t)g,
      (__attribute__((address_space(3))) void*)(unsigned int)(size_t)l,
      16, 0, 0);
}

__device__ inline float block_sum(float v, float* sb) {
  #pragma unroll
  for (int o = 32; o; o >>= 1) v += __shfl_down(v, o);
  int w = threadIdx.x >> 6;
  if ((threadIdx.x & 63) == 0) sb[w] = v;
  __syncthreads();
  float s = sb[0] + sb[1] + sb[2] + sb[3];
  __syncthreads();
  return s;
}

// ---------------- weight conversion ----------------
__global__ __launch_bounds__(256) void k_cast(const float* __restrict__ s, u16* __restrict__ d) {
  size_t i = ((size_t)blockIdx.x * 256 + threadIdx.x) * 4;
  float4 v = *(const float4*)&s[i];
  u16 o[4] = {f2bf(v.x), f2bf(v.y), f2bf(v.z), f2bf(v.w)};
  *(uint2*)&d[i] = *(uint2*)o;
}

// transpose+cast: src f32 [K][N] -> dst bf16 [N][K]; blockIdx.z = layer
__global__ __launch_bounds__(256) void k_tcast(const float* __restrict__ src, size_t sstride,
                                               u16* __restrict__ dst, size_t dstride,
                                               int K, int N) {
  __shared__ float S[64][65];
  const float* sp = src + (size_t)blockIdx.z * sstride;
  u16* dp = dst + (size_t)blockIdx.z * dstride;
  int n0 = blockIdx.x * 64, k0 = blockIdx.y * 64;
  int tid = threadIdx.x;
  int tr = tid >> 4, tc = (tid & 15) * 4;
  #pragma unroll
  for (int it = 0; it < 4; ++it) {
    int r = tr + it * 16;
    int col = n0 + tc;
    float4 v;
    if (col + 3 < N) v = *(const float4*)&sp[(size_t)(k0 + r) * N + col];
    else {
      v.x = (col + 0 < N) ? sp[(size_t)(k0 + r) * N + col + 0] : 0.f;
      v.y = (col + 1 < N) ? sp[(size_t)(k0 + r) * N + col + 1] : 0.f;
      v.z = (col + 2 < N) ? sp[(size_t)(k0 + r) * N + col + 2] : 0.f;
      v.w = 0.f;
    }
    S[r][tc + 0] = v.x; S[r][tc + 1] = v.y; S[r][tc + 2] = v.z; S[r][tc + 3] = v.w;
  }
  __syncthreads();
  #pragma unroll
  for (int it = 0; it < 4; ++it) {
    int rn = tr + it * 16;
    if (n0 + rn >= N) continue;
    u16 o[4];
    o[0] = f2bf(S[tc + 0][rn]); o[1] = f2bf(S[tc + 1][rn]);
    o[2] = f2bf(S[tc + 2][rn]); o[3] = f2bf(S[tc + 3][rn]);
    *(uint2*)&dp[(size_t)(n0 + rn) * K + k0 + tc] = *(uint2*)o;
  }
}

// ---------------- embedding gather ----------------
__global__ __launch_bounds__(256) void k_embed(const int* x, const float* embed, float* h) {
  int t = blockIdx.x, d = threadIdx.x;
  int row = x[t];
  const float4* src = (const float4*)(embed + (size_t)row * 1024);
  float4* dst = (float4*)(h + (size_t)t * 1024);
  dst[d] = src[d];
}

// ---------------- rmsnorm (width 1024) -> bf16 ----------------
__global__ __launch_bounds__(256) void k_rmsnorm(const float* in, const float* w, u16* out) {
  __shared__ float sb[8];
  int t = blockIdx.x, tid = threadIdx.x;
  float4 v = *(const float4*)&in[(size_t)t * 1024 + tid * 4];
  float ss = v.x * v.x + v.y * v.y + v.z * v.z + v.w * v.w;
  float tot = block_sum(ss, sb);
  float rn = rsqrtf(tot / 1024.f + 1e-6f);
  int c = tid * 4;
  size_t b = (size_t)t * 1024 + c;
  u16 o[4] = {f2bf(v.x * rn * w[c + 0]), f2bf(v.y * rn * w[c + 1]),
              f2bf(v.z * rn * w[c + 2]), f2bf(v.w * rn * w[c + 3])};
  *(uint2*)&out[b] = *(uint2*)o;
}

// ---------------- GEMM v2: A bf16 [M][K], B bf16 [N][K] ----------------
enum { EPI_F32 = 0, EPI_QKV = 1, EPI_GELU = 2, EPI_ADD = 3 };

struct GOut {
  void* out;
  const float* aux;
  float *r, *k, *v, *ld, *g, *zx;
};

template <int EPI, int BM, int BN>
__global__ __launch_bounds__(256) void k_gemm2(const u16* __restrict__ A,
                                               const u16* __restrict__ Bt,
                                               int N, int K, GOut go) {
  __shared__ __align__(16) u16 As[BM][64];
  __shared__ __align__(16) u16 Bs[BN][64];
  constexpr int FR = BM / 32, FC = BN / 32;
  int tid = threadIdx.x, lane = tid & 63, wid = tid >> 6;
  int m0 = blockIdx.x * BM, n0 = blockIdx.y * BN;
  int wr = (wid >> 1) * (BM / 2), wc = (wid & 1) * (BN / 2);
  int lr = lane & 15, lk8 = (lane >> 4) * 8;
  f32x4 acc[FR][FC] = {};
  for (int k0 = 0; k0 < K; k0 += 64) {
    __syncthreads();
    #pragma unroll
    for (int it = 0; it < BM / 32; ++it) {
      int rb = wid * (BM / 4) + it * 8;
      int r = rb + (lane >> 3), cc = (lane & 7) * 8;
      gload16(&A[(size_t)(m0 + r) * K + k0 + cc], &As[rb][0]);
    }
    #pragma unroll
    for (int it = 0; it < BN / 32; ++it) {
      int rb = wid * (BN / 4) + it * 8;
      int r = rb + (lane >> 3), cc = (lane & 7) * 8;
      gload16(&Bt[(size_t)(n0 + r) * K + k0 + cc], &Bs[rb][0]);
    }
    __syncthreads();
    #pragma unroll
    for (int kb = 0; kb < 64; kb += 32) {
      s16x8 af[FR], bf[FC];
      #pragma unroll
      for (int i = 0; i < FR; ++i) af[i] = *(const s16x8*)&As[wr + i * 16 + lr][kb + lk8];
      #pragma unroll
      for (int j = 0; j < FC; ++j) bf[j] = *(const s16x8*)&Bs[wc + j * 16 + lr][kb + lk8];
      #pragma unroll
      for (int i = 0; i < FR; ++i)
        #pragma unroll
        for (int j = 0; j < FC; ++j)
          acc[i][j] = __builtin_amdgcn_mfma_f32_16x16x32_bf16(af[i], bf[j], acc[i][j], 0, 0, 0);
    }
  }
  #pragma unroll
  for (int i = 0; i < FR; ++i)
    #pragma unroll
    for (int j = 0; j < FC; ++j) {
      int row = m0 + wr + i * 16 + ((lane >> 4) << 2);
      int col = n0 + wc + j * 16 + lr;
      if (col >= N) continue;
      #pragma unroll
      for (int r_ = 0; r_ < 4; ++r_) {
        float v = acc[i][j][r_];
        size_t rr = (size_t)(row + r_);
        if constexpr (EPI == EPI_F32) {
          ((float*)go.out)[rr * (size_t)N + col] = v;
        } else if constexpr (EPI == EPI_GELU) {
          ((u16*)go.out)[rr * (size_t)N + col] =
              f2bf(0.5f * v * (1.f + erff(v * 0.70710678118654752f)));
        } else if constexpr (EPI == EPI_ADD) {
          ((float*)go.out)[rr * (size_t)N + col] += v;
        } else if constexpr (EPI == EPI_QKV) {
          if (col < 1024)       go.r[rr * 1024 + col] = v;
          else if (col < 2048)  go.k[rr * 1024 + col - 1024] = v;
          else if (col < 3072)  go.v[rr * 1024 + col - 2048] = v;
          else if (col < 4096)  go.ld[rr * 1024 + col - 3072] = -expf(v + go.aux[col - 3072]);
          else if (col < 5120)  go.g[rr * 1024 + col - 4096] = v * sigf(v);
          else                  go.zx[rr * 4256 + col - 5120] = v;
        }
      }
    }
}

// ---------------- rwkv: per-chunk cumulative decays ----------------
__global__ __launch_bounds__(256) void k_rwkv_pre(const float* rbuf, const float* kbuf,
                                                  const float* ldbuf, float* gex, u16* rt,
                                                  u16* khT, float* eL) {
  int c = blockIdx.x;
  int h = blockIdx.y * 4 + (threadIdx.x >> 6);
  int k = threadIdx.x & 63;
  size_t col = (size_t)h * 64 + k;
  float g = 0.f;
  for (int i = 0; i < 64; ++i) {
    size_t idx = (size_t)(c * 64 + i) * 1024 + col;
    gex[idx] = g;
    rt[idx] = f2bf(rbuf[idx] * expf(g));
    g += ldbuf[idx];
  }
  float gL = g;
  eL[((size_t)c * 16 + h) * 64 + k] = expf(gL);
  g = 0.f;
  for (int i = 0; i < 64; ++i) {
    size_t idx = (size_t)(c * 64 + i) * 1024 + col;
    g += ldbuf[idx];
    khT[(((size_t)c * 16 + h) * 64 + k) * 64 + i] = f2bf(kbuf[idx] * expf(fminf(gL - g, 0.f)));
  }
}

// intra-chunk scores
__global__ __launch_bounds__(256) void k_rwkvG(const float* rbuf, const float* kbuf,
                                               const float* gex, const float* u, u16* G) {
  __shared__ float rS[64][65], kS[64][65], gS[64][65];
  __shared__ float uS[64];
  int c = blockIdx.x, h = blockIdx.y, tid = threadIdx.x;
  #pragma unroll
  for (int it = 0; it < 4; ++it) {
    int idx = it * 256 + tid;
    int r = idx >> 4, c4 = (idx & 15) * 4;
    size_t base = (size_t)(c * 64 + r) * 1024 + h * 64 + c4;
    float4 rv = *(const float4*)&rbuf[base];
    float4 kv = *(const float4*)&kbuf[base];
    float4 gv = *(const float4*)&gex[base];
    rS[r][c4] = rv.x; rS[r][c4+1] = rv.y; rS[r][c4+2] = rv.z; rS[r][c4+3] = rv.w;
    kS[r][c4] = kv.x; kS[r][c4+1] = kv.y; kS[r][c4+2] = kv.z; kS[r][c4+3] = kv.w;
    gS[r][c4] = gv.x; gS[r][c4+1] = gv.y; gS[r][c4+2] = gv.z; gS[r][c4+3] = gv.w;
  }
  if (tid < 64) uS[tid] = u[h * 64 + tid];
  __syncthreads();
  int i = tid & 63, sg = tid >> 6;
  float acc[16] = {};
  float accd = 0.f;
  for (int k = 0; k < 64; ++k) {
    float rv = rS[i][k], gi = gS[i][k];
    accd += rv * uS[k] * kS[i][k];
    #pragma unroll
    for (int j = 0; j < 16; ++j) {
      int s = sg * 16 + j;
      int sp1 = (s < 63) ? s + 1 : 63;
      acc[j] += rv * kS[s][k] * expf(fminf(gi - gS[sp1][k], 0.f));
    }
  }
  #pragma unroll
  for (int j = 0; j < 16; ++j) {
    int s = sg * 16 + j;
    float v = (s < i) ? acc[j] : ((s == i) ? accd : 0.f);
    G[(((size_t)c * 16 + h) * 64 + i) * 64 + s] = f2bf(v);
  }
}

// U_c = khT @ V  (parallel over chunks x heads)
__global__ __launch_bounds__(256) void k_rwkvU(const u16* __restrict__ khT,
                                               const float* __restrict__ vbuf,
                                               float* __restrict__ U) {
  __shared__ __align__(16) u16 khS[64][64];
  __shared__ __align__(16) u16 vtS[64][72];
  int c = blockIdx.x, h = blockIdx.y, tid = threadIdx.x;
  int lane = tid & 63, wid = tid >> 6, lr = lane & 15, lk8 = (lane >> 4) * 8;
  size_t gb = ((size_t)c * 16 + h) * 64;
  #pragma unroll
  for (int it = 0; it < 2; ++it) {
    int rb = wid * 16 + it * 8;
    int r = rb + (lane >> 3), cc = (lane & 7) * 8;
    gload16(&khT[(gb + r) * 64 + cc], &khS[rb][0]);
  }
  #pragma unroll
  for (int it = 0; it < 4; ++it) {
    int idx = it * 256 + tid;
    int s = idx >> 4, v4 = (idx & 15) * 4;
    float4 vv = *(const float4*)&vbuf[(size_t)(c * 64 + s) * 1024 + h * 64 + v4];
    vtS[v4 + 0][s] = f2bf(vv.x); vtS[v4 + 1][s] = f2bf(vv.y);
    vtS[v4 + 2][s] = f2bf(vv.z); vtS[v4 + 3][s] = f2bf(vv.w);
  }
  __syncthreads();
  int wr = (wid >> 1) * 32, wc = (wid & 1) * 32;
  f32x4 acc[2][2] = {};
  #pragma unroll
  for (int kb = 0; kb < 64; kb += 32) {
    s16x8 a[2], b[2];
    #pragma unroll
    for (int i = 0; i < 2; ++i) a[i] = *(const s16x8*)&khS[wr + i * 16 + lr][kb + lk8];
    #pragma unroll
    for (int j = 0; j < 2; ++j) b[j] = *(const s16x8*)&vtS[wc + j * 16 + lr][kb + lk8];
    #pragma unroll
    for (int i = 0; i < 2; ++i)
      #pragma unroll
      for (int j = 0; j < 2; ++j)
        acc[i][j] = __builtin_amdgcn_mfma_f32_16x16x32_bf16(a[i], b[j], acc[i][j], 0, 0, 0);
  }
  #pragma unroll
  for (int i = 0; i < 2; ++i)
    #pragma unroll
    for (int j = 0; j < 2; ++j) {
      int row = wr + i * 16 + ((lane >> 4) << 2);
      int col = wc + j * 16 + lr;
      #pragma unroll
      for (int r_ = 0; r_ < 4; ++r_)
        U[(gb + row + r_) * 64 + col] = acc[i][j][r_];
    }
}

// sequential 16-step state scan (rwkv): S = diag(eL) S + U; snapshot S_in as bf16
__global__ __launch_bounds__(256) void k_rwkv_scan(const float* __restrict__ U,
                                                   const float* __restrict__ eL,
                                                   u16* __restrict__ Sall) {
  int h = blockIdx.x, tid = threadIdx.x;
  int k = tid >> 2, v0 = (tid & 3) * 16;
  float S[16] = {};
  for (int c = 0; c < 16; ++c) {
    size_t gb = ((size_t)c * 16 + h) * 64;
    u16 tmp[16];
    #pragma unroll
    for (int j = 0; j < 16; ++j) tmp[j] = f2bf(S[j]);
    *(uint4*)&Sall[(gb + k) * 64 + v0] = *(uint4*)&tmp[0];
    *(uint4*)&Sall[(gb + k) * 64 + v0 + 8] = *(uint4*)&tmp[8];
    float e = eL[gb + k];
    const float4* up = (const float4*)&U[(gb + k) * 64 + v0];
    #pragma unroll
    for (int q = 0; q < 4; ++q) {
      float4 uv = up[q];
      S[q * 4 + 0] = e * S[q * 4 + 0] + uv.x;
      S[q * 4 + 1] = e * S[q * 4 + 1] + uv.y;
      S[q * 4 + 2] = e * S[q * 4 + 2] + uv.z;
      S[q * 4 + 3] = e * S[q * 4 + 3] + uv.w;
    }
  }
}

// O_c = rt@S_in + G@V, fused with o*g -> bf16  (parallel)
__global__ __launch_bounds__(256) void k_rwkvO(const u16* __restrict__ rt,
                                               const u16* __restrict__ Gb,
                                               const u16* __restrict__ Sall,
                                               const float* __restrict__ vbuf,
                                               const float* __restrict__ gbuf,
                                               u16* __restrict__ og) {
  __shared__ __align__(16) u16 rtS[64][64], GS[64][64];
  __shared__ __align__(16) u16 StS[64][72], vtS[64][72];
  int c = blockIdx.x, h = blockIdx.y, tid = threadIdx.x;
  int lane = tid & 63, wid = tid >> 6, lr = lane & 15, lk8 = (lane >> 4) * 8;
  size_t gb = ((size_t)c * 16 + h) * 64;
  #pragma unroll
  for (int it = 0; it < 2; ++it) {
    int rb = wid * 16 + it * 8;
    int r = rb + (lane >> 3), cc = (lane & 7) * 8;
    gload16(&rt[(size_t)(c * 64 + r) * 1024 + h * 64 + cc], &rtS[rb][0]);
    gload16(&Gb[(gb + r) * 64 + cc], &GS[rb][0]);
  }
  #pragma unroll
  for (int it = 0; it < 2; ++it) {
    int idx = it * 256 + tid;
    int k = idx >> 3, c8 = (idx & 7) * 8;
    uint4 ld = *(const uint4*)&Sall[(gb + k) * 64 + c8];
    const u16* pv = (const u16*)&ld;
    #pragma unroll
    for (int jj = 0; jj < 8; ++jj) StS[c8 + jj][k] = pv[jj];
  }
  #pragma unroll
  for (int it = 0; it < 4; ++it) {
    int idx = it * 256 + tid;
    int s = idx >> 4, v4 = (idx & 15) * 4;
    float4 vv = *(const float4*)&vbuf[(size_t)(c * 64 + s) * 1024 + h * 64 + v4];
    vtS[v4 + 0][s] = f2bf(vv.x); vtS[v4 + 1][s] = f2bf(vv.y);
    vtS[v4 + 2][s] = f2bf(vv.z); vtS[v4 + 3][s] = f2bf(vv.w);
  }
  __syncthreads();
  int wr = (wid >> 1) * 32, wc = (wid & 1) * 32;
  f32x4 acc[2][2] = {};
  #pragma unroll
  for (int kb = 0; kb < 64; kb += 32) {
    s16x8 aR[2], aG[2], bS[2], bV[2];
    #pragma unroll
    for (int i = 0; i < 2; ++i) {
      aR[i] = *(const s16x8*)&rtS[wr + i * 16 + lr][kb + lk8];
      aG[i] = *(const s16x8*)&GS[wr + i * 16 + lr][kb + lk8];
    }
    #pragma unroll
    for (int j = 0; j < 2; ++j) {
      bS[j] = *(const s16x8*)&StS[wc + j * 16 + lr][kb + lk8];
      bV[j] = *(const s16x8*)&vtS[wc + j * 16 + lr][kb + lk8];
    }
    #pragma unroll
    for (int i = 0; i < 2; ++i)
      #pragma unroll
      for (int j = 0; j < 2; ++j) {
        acc[i][j] = __builtin_amdgcn_mfma_f32_16x16x32_bf16(aR[i], bS[j], acc[i][j], 0, 0, 0);
        acc[i][j] = __builtin_amdgcn_mfma_f32_16x16x32_bf16(aG[i], bV[j], acc[i][j], 0, 0, 0);
      }
  }
  #pragma unroll
  for (int i = 0; i < 2; ++i)
    #pragma unroll
    for (int j = 0; j < 2; ++j) {
      int row = c * 64 + wr + i * 16 + ((lane >> 4) << 2);
      int col = h * 64 + wc + j * 16 + lr;
      #pragma unroll
      for (int r_ = 0; r_ < 4; ++r_) {
        size_t idx = (size_t)(row + r_) * 1024 + col;
        og[idx] = f2bf(acc[i][j][r_] * gbuf[idx]);
      }
    }
}

// ---------------- causal depthwise conv (K=4) + silu ----------------
__global__ void k_conv(const float* zx, const float* cw, float* xc) {
  int c = blockIdx.x * 256 + threadIdx.x;
  int t = blockIdx.y;
  if (c >= CCONV) return;
  float4 w = *(const float4*)&cw[c * 4];
  float acc = 0.f;
  if (t - 3 >= 0) acc += zx[(size_t)(t - 3) * NWIN + 2048 + c] * w.x;
  if (t - 2 >= 0) acc += zx[(size_t)(t - 2) * NWIN + 2048 + c] * w.y;
  if (t - 1 >= 0) acc += zx[(size_t)(t - 1) * NWIN + 2048 + c] * w.z;
  acc += zx[(size_t)t * NWIN + 2048 + c] * w.w;
  xc[(size_t)t * CCONV + c] = acc * sigf(acc);
}

// ---------------- dt softplus + per-chunk prefix of log dA ----------------
__global__ __launch_bounds__(256) void k_dtla(const float* __restrict__ zx,
                                              const float* __restrict__ dt_bias,
                                              const float* __restrict__ A_log,
                                              float* __restrict__ dtb, float* __restrict__ la) {
  __shared__ float ldaS[64][33];
  int c = blockIdx.x, tid = threadIdx.x;
  #pragma unroll
  for (int it = 0; it < 8; ++it) {
    int e = it * 256 + tid;
    int i = e >> 5, j = e & 31;
    float x = zx[(size_t)(c * 64 + i) * NWIN + 4224 + j] + dt_bias[j];
    float sp = (x > 20.f) ? x : log1pf(expf(x));
    dtb[(size_t)(c * 64 + i) * 32 + j] = sp;
    ldaS[i][j] = -sp * expf(A_log[j]);
  }
  __syncthreads();
  if (tid < 32) {
    float g = 0.f;
    for (int i = 0; i < 64; ++i) {
      g += ldaS[i][tid];
      la[((size_t)c * 32 + tid) * 64 + i] = g;
    }
  }
}

// ---------------- BC[i][s] = B_s . C_i ----------------
__global__ __launch_bounds__(256) void k_bc(const float* xc, float* BC) {
  __shared__ float Bc[64][65], Cc[64][65];
  int c = blockIdx.x, tid = threadIdx.x;
  #pragma unroll
  for (int it = 0; it < 4; ++it) {
    int idx = it * 256 + tid;
    int r = idx >> 4, c4 = (idx & 15) * 4;
    float4 b4 = *(const float4*)&xc[(size_t)(c * 64 + r) * CCONV + 2048 + c4];
    float4 cv = *(const float4*)&xc[(size_t)(c * 64 + r) * CCONV + 2112 + c4];
    Bc[r][c4] = b4.x; Bc[r][c4+1] = b4.y; Bc[r][c4+2] = b4.z; Bc[r][c4+3] = b4.w;
    Cc[r][c4] = cv.x; Cc[r][c4+1] = cv.y; Cc[r][c4+2] = cv.z; Cc[r][c4+3] = cv.w;
  }
  __syncthreads();
  int i = tid & 63, sg = tid >> 6;
  float acc[16] = {};
  for (int d = 0; d < 64; ++d) {
    float cv = Cc[i][d];
    #pragma unroll
    for (int j = 0; j < 16; ++j) acc[j] += Bc[sg * 16 + j][d] * cv;
  }
  #pragma unroll
  for (int j = 0; j < 16; ++j)
    BC[((size_t)c * 64 + i) * 64 + sg * 16 + j] = acc[j];
}

// ---------------- M[i][s] ----------------
__global__ __launch_bounds__(256) void k_m(const float* la, const float* dtb,
                                           const float* BC, u16* Mb) {
  int c = blockIdx.x, h = blockIdx.y, tid = threadIdx.x;
  int i = tid & 63, sg = tid >> 6;
  float lai = la[((size_t)c * 32 + h) * 64 + i];
  #pragma unroll
  for (int j = 0; j < 16; ++j) {
    int s = sg * 16 + j;
    float v = 0.f;
    if (s <= i) {
      float las = la[((size_t)c * 32 + h) * 64 + s];
      v = expf(fminf(lai - las, 0.f)) * dtb[(size_t)(c * 64 + s) * 32 + h] *
          BC[((size_t)c * 64 + i) * 64 + s];
    }
    Mb[(((size_t)c * 32 + h) * 64 + i) * 64 + s] = f2bf(v);
  }
}

// U_c[p][s] = sum_i f_i x[i][p] B[i][s]
__global__ __launch_bounds__(256) void k_mambaU(const float* __restrict__ xc,
                                                const float* __restrict__ la,
                                                const float* __restrict__ dtb,
                                                float* __restrict__ Um) {
  __shared__ __align__(16) u16 XT[64][72], BT[64][72];
  __shared__ float fS[64];
  int c = blockIdx.x, h = blockIdx.y, tid = threadIdx.x;
  int lane = tid & 63, wid = tid >> 6, lr = lane & 15, lk8 = (lane >> 4) * 8;
  size_t lb = ((size_t)c * 32 + h) * 64;
  if (tid < 64) {
    float la63 = la[lb + 63];
    fS[tid] = dtb[(size_t)(c * 64 + tid) * 32 + h] * expf(fminf(la63 - la[lb + tid], 0.f));
  }
  __syncthreads();
  #pragma unroll
  for (int it = 0; it < 4; ++it) {
    int idx = it * 256 + tid;
    int t = idx >> 4, p4 = (idx & 15) * 4;
    float f = fS[t];
    float4 xv = *(const float4*)&xc[(size_t)(c * 64 + t) * CCONV + h * 64 + p4];
    XT[p4 + 0][t] = f2bf(f * xv.x); XT[p4 + 1][t] = f2bf(f * xv.y);
    XT[p4 + 2][t] = f2bf(f * xv.z); XT[p4 + 3][t] = f2bf(f * xv.w);
    float4 bv = *(const float4*)&xc[(size_t)(c * 64 + t) * CCONV + 2048 + p4];
    BT[p4 + 0][t] = f2bf(bv.x); BT[p4 + 1][t] = f2bf(bv.y);
    BT[p4 + 2][t] = f2bf(bv.z); BT[p4 + 3][t] = f2bf(bv.w);
  }
  __syncthreads();
  int wr = (wid >> 1) * 32, wc = (wid & 1) * 32;
  f32x4 acc[2][2] = {};
  #pragma unroll
  for (int kb = 0; kb < 64; kb += 32) {
    s16x8 a[2], b[2];
    #pragma unroll
    for (int i = 0; i < 2; ++i) a[i] = *(const s16x8*)&XT[wr + i * 16 + lr][kb + lk8];
    #pragma unroll
    for (int j = 0; j < 2; ++j) b[j] = *(const s16x8*)&BT[wc + j * 16 + lr][kb + lk8];
    #pragma unroll
    for (int i = 0; i < 2; ++i)
      #pragma unroll
      for (int j = 0; j < 2; ++j)
        acc[i][j] = __builtin_amdgcn_mfma_f32_16x16x32_bf16(a[i], b[j], acc[i][j], 0, 0, 0);
  }
  #pragma unroll
  for (int i = 0; i < 2; ++i)
    #pragma unroll
    for (int j = 0; j < 2; ++j) {
      int row = wr + i * 16 + ((lane >> 4) << 2);
      int col = wc + j * 16 + lr;
      #pragma unroll
      for (int r_ = 0; r_ < 4; ++r_)
        Um[(lb + row + r_) * 64 + col] = acc[i][j][r_];
    }
}

// mamba state scan: S = e^{la63} S + U; snapshot bf16
__global__ __launch_bounds__(256) void k_mamba_scan(const float* __restrict__ Um,
                                                    const float* __restrict__ la,
                                                    u16* __restrict__ hall) {
  int h = blockIdx.x, tid = threadIdx.x;
  int p = tid >> 2, s0 = (tid & 3) * 16;
  float S[16] = {};
  for (int c = 0; c < 16; ++c) {
    size_t lb = ((size_t)c * 32 + h) * 64;
    u16 tmp[16];
    #pragma unroll
    for (int j = 0; j < 16; ++j) tmp[j] = f2bf(S[j]);
    *(uint4*)&hall[(lb + p) * 64 + s0] = *(uint4*)&tmp[0];
    *(uint4*)&hall[(lb + p) * 64 + s0 + 8] = *(uint4*)&tmp[8];
    float e = expf(la[lb + 63]);
    const float4* up = (const float4*)&Um[(lb + p) * 64 + s0];
    #pragma unroll
    for (int q = 0; q < 4; ++q) {
      float4 uv = up[q];
      S[q * 4 + 0] = e * S[q * 4 + 0] + uv.x;
      S[q * 4 + 1] = e * S[q * 4 + 1] + uv.y;
      S[q * 4 + 2] = e * S[q * 4 + 2] + uv.z;
      S[q * 4 + 3] = e * S[q * 4 + 3] + uv.w;
    }
  }
}

// Y_c = M@X + (e^{la} C)@h_in^T  (parallel)
__global__ __launch_bounds__(256) void k_mambaY(const u16* __restrict__ Mb,
                                                const u16* __restrict__ hall,
                                                const float* __restrict__ xc,
                                                const float* __restrict__ la,
                                                float* __restrict__ ymb) {
  __shared__ __align__(16) u16 MS[64][64], hS[64][64];
  __shared__ __align__(16) u16 CtS[64][72], XT2[64][72];
  __shared__ float eS[64];
  int c = blockIdx.x, h = blockIdx.y, tid = threadIdx.x;
  int lane = tid & 63, wid = tid >> 6, lr = lane & 15, lk8 = (lane >> 4) * 8;
  size_t lb = ((size_t)c * 32 + h) * 64;
  if (tid < 64) eS[tid] = expf(la[lb + tid]);
  #pragma unroll
  for (int it = 0; it < 2; ++it) {
    int rb = wid * 16 + it * 8;
    int r = rb + (lane >> 3), cc = (lane & 7) * 8;
    gload16(&Mb[(lb + r) * 64 + cc], &MS[rb][0]);
    gload16(&hall[(lb + r) * 64 + cc], &hS[rb][0]);
  }
  __syncthreads();
  #pragma unroll
  for (int it = 0; it < 4; ++it) {
    int idx = it * 256 + tid;
    int t = idx >> 4, s4 = (idx & 15) * 4;
    float ei = eS[t];
    float4 cv = *(const float4*)&xc[(size_t)(c * 64 + t) * CCONV + 2112 + s4];
    CtS[t][s4 + 0] = f2bf(ei * cv.x); CtS[t][s4 + 1] = f2bf(ei * cv.y);
    CtS[t][s4 + 2] = f2bf(ei * cv.z); CtS[t][s4 + 3] = f2bf(ei * cv.w);
    float4 xv = *(const float4*)&xc[(size_t)(c * 64 + t) * CCONV + h * 64 + s4];
    XT2[s4 + 0][t] = f2bf(xv.x); XT2[s4 + 1][t] = f2bf(xv.y);
    XT2[s4 + 2][t] = f2bf(xv.z); XT2[s4 + 3][t] = f2bf(xv.w);
  }
  __syncthreads();
  int wr = (wid >> 1) * 32, wc = (wid & 1) * 32;
  f32x4 acc[2][2] = {};
  #pragma unroll
  for (int kb = 0; kb < 64; kb += 32) {
    s16x8 aM[2], aC[2], bX[2], bH[2];
    #pragma unroll
    for (int i = 0; i < 2; ++i) {
      aM[i] = *(const s16x8*)&MS[wr + i * 16 + lr][kb + lk8];
      aC[i] = *(const s16x8*)&CtS[wr + i * 16 + lr][kb + lk8];
    }
    #pragma unroll
    for (int j = 0; j < 2; ++j) {
      bX[j] = *(const s16x8*)&XT2[wc + j * 16 + lr][kb + lk8];
      bH[j] = *(const s16x8*)&hS[wc + j * 16 + lr][kb + lk8];
    }
    #pragma unroll
    for (int i = 0; i < 2; ++i)
      #pragma unroll
      for (int j = 0; j < 2; ++j) {
        acc[i][j] = __builtin_amdgcn_mfma_f32_16x16x32_bf16(aM[i], bX[j], acc[i][j], 0, 0, 0);
        acc[i][j] = __builtin_amdgcn_mfma_f32_16x16x32_bf16(aC[i], bH[j], acc[i][j], 0, 0, 0);
      }
  }
  #pragma unroll
  for (int i = 0; i < 2; ++i)
    #pragma unroll
    for (int j = 0; j < 2; ++j) {
      int row = c * 64 + wr + i * 16 + ((lane >> 4) << 2);
      int col = h * 64 + wc + j * 16 + lr;
      #pragma unroll
      for (int r_ = 0; r_ < 4; ++r_)
        ymb[(size_t)(row + r_) * 2048 + col] = acc[i][j][r_];
    }
}

// ---------------- ym: +Dskip*x, *silu(z), rmsnorm(2048) -> bf16 ----------------
__global__ __launch_bounds__(256) void k_ymn(const float* ymb, const float* xc,
                                             const float* zx, const float* Dsk,
                                             const float* mnw, u16* out) {
  __shared__ float sb[8];
  int t = blockIdx.x, tid = threadIdx.x;
  float vals[8];
  float ss = 0.f;
  #pragma unroll
  for (int j = 0; j < 8; ++j) {
    int cidx = j * 256 + tid;
    float yv = ymb[(size_t)t * 2048 + cidx] + Dsk[cidx >> 6] * xc[(size_t)t * CCONV + cidx];
    float zv = zx[(size_t)t * NWIN + cidx];
    float val = yv * zv * sigf(zv);
    vals[j] = val;
    ss += val * val;
  }
  float tot = block_sum(ss, sb);
  float rn = rsqrtf(tot / 2048.f + 1e-6f);
  #pragma unroll
  for (int j = 0; j < 8; ++j) {
    int cidx = j * 256 + tid;
    out[(size_t)t * 2048 + cidx] = f2bf(vals[j] * rn * mnw[cidx]);
  }
}

// ---------------- gate + residual ----------------
__global__ __launch_bounds__(256) void k_gate(const float* rw, const float* mb,
                                              const float* gw, const float* gb, float* h) {
  __shared__ float sb[8];
  int t = blockIdx.x, tid = threadIdx.x;
  float s = 0.f;
  #pragma unroll
  for (int j = 0; j < 4; ++j) {
    int d = j * 256 + tid;
    s += rw[(size_t)t * 1024 + d] * gw[d] + mb[(size_t)t * 1024 + d] * gw[1024 + d];
  }
  float tot = block_sum(s, sb);
  float gate = sigf(tot + gb[0]);
  #pragma unroll
  for (int j = 0; j < 4; ++j) {
    int d = j * 256 + tid;
    h[(size_t)t * 1024 + d] += gate * rw[(size_t)t * 1024 + d] +
                               (1.f - gate) * mb[(size_t)t * 1024 + d];
  }
}

// =======================================================================
extern "C" void kernel_launch(void* const* d_in, const int* in_sizes, int n_in,
                              void* d_out, int out_size, void* d_ws, size_t ws_size,
                              hipStream_t stream) {
  const int*   x       = (const int*)d_in[0];
  const float* embed   = (const float*)d_in[1];
  const float* ln_w    = (const float*)d_in[2];
  const float* Wr      = (const float*)d_in[3];
  const float* Wk      = (const float*)d_in[4];
  const float* Wv      = (const float*)d_in[5];
  const float* Ww      = (const float*)d_in[6];
  const float* w_bias  = (const float*)d_in[7];
  const float* u       = (const float*)d_in[8];
  const float* Wg      = (const float*)d_in[9];
  const float* Wo      = (const float*)d_in[10];
  const float* Win     = (const float*)d_in[11];
  const float* conv_w  = (const float*)d_in[12];
  const float* dt_bias = (const float*)d_in[13];
  const float* A_log   = (const float*)d_in[14];
  const float* Dskip   = (const float*)d_in[15];
  const float* mnorm_w = (const float*)d_in[16];
  const float* Wout_m  = (const float*)d_in[17];
  const float* gate_w  = (const float*)d_in[18];
  const float* gate_b  = (const float*)d_in[19];
  const float* ffn_ln  = (const float*)d_in[20];
  const float* W1      = (const float*)d_in[21];
  const float* W2      = (const float*)d_in[22];
  const float* ln_out  = (const float*)d_in[23];

  char* p = (char*)d_ws;
  auto alloc = [&](size_t bytes) {
    char* r = p;
    p += (bytes + 255) & ~(size_t)255;
    return r;
  };
  // bf16 weights (persist across the launch)
  u16* embB = (u16*)alloc((size_t)VOCABSZ * 1024 * 2);
  u16* Wpk  = (u16*)alloc((size_t)NLAYER * PKROWS * 1024 * 2);
  u16* WoT  = (u16*)alloc((size_t)NLAYER * 1024 * 1024 * 2);
  u16* WomT = (u16*)alloc((size_t)NLAYER * 1024 * 2048 * 2);
  u16* W1T  = (u16*)alloc((size_t)NLAYER * 4096 * 1024 * 2);
  u16* W2T  = (u16*)alloc((size_t)NLAYER * 1024 * 4096 * 2);
  // activations
  float* h        = (float*)alloc((size_t)T * 1024 * 4);
  u16*   nx       = (u16*)alloc((size_t)T * 1024 * 2);
  float* rbuf     = (float*)alloc((size_t)T * 1024 * 4);
  float* kbuf     = (float*)alloc((size_t)T * 1024 * 4);
  float* vbuf     = (float*)alloc((size_t)T * 1024 * 4);
  float* ldbuf    = (float*)alloc((size_t)T * 1024 * 4);
  float* gbuf     = (float*)alloc((size_t)T * 1024 * 4);
  float* zx       = (float*)alloc((size_t)T * NWIN * 4);
  float* gex      = (float*)alloc((size_t)T * 1024 * 4);
  u16*   rt       = (u16*)alloc((size_t)T * 1024 * 2);
  u16*   khT      = (u16*)alloc((size_t)T * 1024 * 2);
  float* eL       = (float*)alloc((size_t)NCHUNK * 16 * 64 * 4);
  u16*   Gb       = (u16*)alloc((size_t)NCHUNK * 16 * 64 * 64 * 2);
  float* Urw      = (float*)alloc((size_t)NCHUNK * 16 * 64 * 64 * 4);
  u16*   Sall     = (u16*)alloc((size_t)NCHUNK * 16 * 64 * 64 * 2);
  u16*   og       = (u16*)alloc((size_t)T * 1024 * 2);
  float* out_rwkv = (float*)alloc((size_t)T * 1024 * 4);
  float* xc       = (float*)alloc((size_t)T * CCONV * 4);
  float* dtb      = (float*)alloc((size_t)T * 32 * 4);
  float* la       = (float*)alloc((size_t)NCHUNK * 32 * 64 * 4);
  float* BC       = (float*)alloc((size_t)NCHUNK * 64 * 64 * 4);
  u16*   Mb       = (u16*)alloc((size_t)NCHUNK * 32 * 64 * 64 * 2);
  float* Um       = (float*)alloc((size_t)NCHUNK * 32 * 64 * 64 * 4);
  u16*   hall     = (u16*)alloc((size_t)NCHUNK * 32 * 64 * 64 * 2);
  float* ymb      = (float*)alloc((size_t)T * 2048 * 4);
  u16*   ymn      = (u16*)alloc((size_t)T * 2048 * 2);
  float* out_mam  = (float*)alloc((size_t)T * 1024 * 4);
  u16*   ffa      = (u16*)alloc((size_t)T * FFH * 2);

  const size_t PKS = (size_t)PKROWS * 1024;

  // ---- weight conversion (once per launch) ----
  k_cast<<<VOCABSZ * 1024 / 1024, 256, 0, stream>>>(embed, embB);
  k_tcast<<<dim3(16, 16, 4), 256, 0, stream>>>(Wr, 1024 * 1024, Wpk, PKS, 1024, 1024);
  k_tcast<<<dim3(16, 16, 4), 256, 0, stream>>>(Wk, 1024 * 1024, Wpk + 1024 * 1024, PKS, 1024, 1024);
  k_tcast<<<dim3(16, 16, 4), 256, 0, stream>>>(Wv, 1024 * 1024, Wpk + 2048 * 1024, PKS, 1024, 1024);
  k_tcast<<<dim3(16, 16, 4), 256, 0, stream>>>(Ww, 1024 * 1024, Wpk + 3072 * 1024, PKS, 1024, 1024);
  k_tcast<<<dim3(16, 16, 4), 256, 0, stream>>>(Wg, 1024 * 1024, Wpk + 4096 * 1024, PKS, 1024, 1024);
  k_tcast<<<dim3(67, 16, 4), 256, 0, stream>>>(Win, (size_t)1024 * NWIN, Wpk + (size_t)5120 * 1024, PKS, 1024, NWIN);
  k_tcast<<<dim3(16, 16, 4), 256, 0, stream>>>(Wo, 1024 * 1024, WoT, (size_t)1024 * 1024, 1024, 1024);
  k_tcast<<<dim3(16, 32, 4), 256, 0, stream>>>(Wout_m, (size_t)2048 * 1024, WomT, (size_t)1024 * 2048, 2048, 1024);
  k_tcast<<<dim3(64, 16, 4), 256, 0, stream>>>(W1, (size_t)1024 * 4096, W1T, (size_t)4096 * 1024, 1024, 4096);
  k_tcast<<<dim3(16, 64, 4), 256, 0, stream>>>(W2, (size_t)4096 * 1024, W2T, (size_t)1024 * 4096, 4096, 1024);

  k_embed<<<1024, 256, 0, stream>>>(x, embed, h);

  for (int l = 0; l < NLAYER; ++l) {
    k_rmsnorm<<<1024, 256, 0, stream>>>(h, ln_w + l * 1024, nx);
    {
      GOut go = {};
      go.r = rbuf; go.k = kbuf; go.v = vbuf; go.ld = ldbuf; go.g = gbuf; go.zx = zx;
      go.aux = w_bias + l * 1024;
      k_gemm2<EPI_QKV, 128, 128><<<dim3(8, 74), 256, 0, stream>>>(nx, Wpk + (size_t)l * PKS, PKN, 1024, go);
    }
    // rwkv branch
    k_rwkv_pre<<<dim3(16, 4), 256, 0, stream>>>(rbuf, kbuf, ldbuf, gex, rt, khT, eL);
    k_rwkvG<<<dim3(16, 16), 256, 0, stream>>>(rbuf, kbuf, gex, u + (size_t)l * 1024, Gb);
    k_rwkvU<<<dim3(16, 16), 256, 0, stream>>>(khT, vbuf, Urw);
    k_rwkv_scan<<<16, 256, 0, stream>>>(Urw, eL, Sall);
    k_rwkvO<<<dim3(16, 16), 256, 0, stream>>>(rt, Gb, Sall, vbuf, gbuf, og);
    {
      GOut go = {}; go.out = out_rwkv;
      k_gemm2<EPI_F32, 64, 64><<<dim3(16, 16), 256, 0, stream>>>(og, WoT + (size_t)l * 1024 * 1024, 1024, 1024, go);
    }
    // mamba branch
    k_conv<<<dim3(9, 1024), 256, 0, stream>>>(zx, conv_w + (size_t)l * CCONV * 4, xc);
    k_dtla<<<16, 256, 0, stream>>>(zx, dt_bias + l * 32, A_log + l * 32, dtb, la);
    k_bc<<<16, 256, 0, stream>>>(xc, BC);
    k_m<<<dim3(16, 32), 256, 0, stream>>>(la, dtb, BC, Mb);
    k_mambaU<<<dim3(16, 32), 256, 0, stream>>>(xc, la, dtb, Um);
    k_mamba_scan<<<32, 256, 0, stream>>>(Um, la, hall);
    k_mambaY<<<dim3(16, 32), 256, 0, stream>>>(Mb, hall, xc, la, ymb);
    k_ymn<<<1024, 256, 0, stream>>>(ymb, xc, zx, Dskip + l * 32, mnorm_w + (size_t)l * 2048, ymn);
    {
      GOut go = {}; go.out = out_mam;
      k_gemm2<EPI_F32, 64, 64><<<dim3(16, 16), 256, 0, stream>>>(ymn, WomT + (size_t)l * 1024 * 2048, 1024, 2048, go);
    }
    // gate + residual
    k_gate<<<1024, 256, 0, stream>>>(out_rwkv, out_mam, gate_w + (size_t)l * 2048, gate_b + l, h);
    // FFN
    k_rmsnorm<<<1024, 256, 0, stream>>>(h, ffn_ln + l * 1024, nx);
    {
      GOut go = {}; go.out = ffa;
      k_gemm2<EPI_GELU, 128, 128><<<dim3(8, 32), 256, 0, stream>>>(nx, W1T + (size_t)l * 4096 * 1024, 4096, 1024, go);
    }
    {
      GOut go = {}; go.out = h;
      k_gemm2<EPI_ADD, 64, 64><<<dim3(16, 16), 256, 0, stream>>>(ffa, W2T + (size_t)l * 1024 * 4096, 1024, 4096, go);
    }
  }

  k_rmsnorm<<<1024, 256, 0, stream>>>(h, ln_out, nx);
  {
    GOut go = {}; go.out = d_out;
    k_gemm2<EPI_F32, 128, 128><<<dim3(8, 250), 256, 0, stream>>>(nx, embB, VOCABSZ, 1024, go);
  }
}